// Round 10
// baseline (206.556 us; speedup 1.0000x reference)
//
#include <hip/hip_runtime.h>

typedef __bf16 bf16x8 __attribute__((ext_vector_type(8)));
typedef float f32x4 __attribute__((ext_vector_type(4)));

#define DIM 1024
#define NSEQ 2048

// async 16B global -> LDS DMA (lane-linear: wave-uniform LDS base + lane*16)
#define GL2LDS(g, l) __builtin_amdgcn_global_load_lds( \
    (const __attribute__((address_space(1))) void*)(g), \
    (__attribute__((address_space(3))) void*)(l), 16, 0, 0)

#define MFMA16(a, b, c) __builtin_amdgcn_mfma_f32_16x16x32_bf16(a, b, c, 0, 0, 0)

// ---------------- fused pre-pass: cvt wq/wk/wv + rope cos/sin table + rmsnorm ---
__global__ __launch_bounds__(256) void pre_kernel(const float* __restrict__ wq,
                                                  const float* __restrict__ wk,
                                                  const float* __restrict__ wv,
                                                  __bf16* __restrict__ dq,
                                                  __bf16* __restrict__ dk,
                                                  __bf16* __restrict__ dv,
                                                  float2* __restrict__ tbl,
                                                  int* __restrict__ counters,
                                                  const float* __restrict__ x,
                                                  const float* __restrict__ g,
                                                  __bf16* __restrict__ xo) {
    int bid = blockIdx.x;
    int t = threadIdx.x;
    if (bid == 0 && t < 8) counters[t] = 0;
    if (bid < 3072) {                    // weight conversion
        int slice = bid >> 10;
        const float* s = slice == 0 ? wq : (slice == 1 ? wk : wv);
        __bf16*      d = slice == 0 ? dq : (slice == 1 ? dk : dv);
        int i = ((bid & 1023) * 256 + t) * 4;
        float4 f = *(const float4*)(s + i);
        union { uint2 u; __bf16 h[4]; } p;
        p.h[0] = (__bf16)f.x; p.h[1] = (__bf16)f.y;
        p.h[2] = (__bf16)f.z; p.h[3] = (__bf16)f.w;
        *(uint2*)(d + i) = p.u;
    } else if (bid < 3328) {             // rope table: tbl[pos*32+dp] = {cos,sin}
        int e = (bid - 3072) * 256 + t;
        int pos = e >> 5, dp = e & 31;
        float inv = __expf(-(float)dp * (9.210340371976184f / 32.0f));
        float sn, cs;
        sincosf((float)pos * inv, &sn, &cs);
        tbl[e] = make_float2(cs, sn);
    } else {                             // RMSNorm row
        int row = bid - 3328;
        float4 xv = ((const float4*)(x + (size_t)row * DIM))[t];
        float ss = xv.x*xv.x + xv.y*xv.y + xv.z*xv.z + xv.w*xv.w;
        #pragma unroll
        for (int off = 32; off; off >>= 1) ss += __shfl_xor(ss, off, 64);
        __shared__ float red[4];
        if ((t & 63) == 0) red[t >> 6] = ss;
        __syncthreads();
        ss = red[0] + red[1] + red[2] + red[3];
        float r = rsqrtf(ss * (1.0f / 1024.0f) + 1.1920929e-07f);
        float4 gv = ((const float4*)g)[t];
        union { uint2 u; __bf16 h[4]; } p;
        p.h[0] = (__bf16)(xv.x * r * gv.x);
        p.h[1] = (__bf16)(xv.y * r * gv.y);
        p.h[2] = (__bf16)(xv.z * r * gv.z);
        p.h[3] = (__bf16)(xv.w * r * gv.w);
        *(uint2*)(xo + (size_t)row * DIM + t * 4) = p.u;
    }
}

// ---------------- GEMM body v2: 2-PHASE PIPELINE (T3 minimal) -------------------
// R9 pm: single-buffer stage->drain->compute exposes the full tile DMA before
// every K-step (m97 structural stall); qkv sat at 15% MfmaUtil. New structure:
// BK=32, DOUBLE-buffered LDS (32KB total, 3 blocks/CU kept), ONE barrier/step:
//   stage(kt+1 -> other buf); ds_read+MFMA(cur buf); __syncthreads (drains DMA)
// The next tile's DMA overlaps this step's compute; the end-of-step barrier's
// implicit vmcnt(0) finds it complete. Hazard-free: stage targets the buffer NOT
// being read; overwrite of buf read at kt-1 is fenced by that step's barrier.
// Swizzle (stride 32 rows = 64B): s(row) = (row&3)^((row>>2)&3); source
// pre-swizzled so LDS[R][cb] = G[R][cb^s(R)]; readers use cb = lq^s(row) ->
// exact 2-way on both sides (free).
template <typename CT, bool ROPE>
__device__ __forceinline__ void gemm_body(const __bf16* __restrict__ A,
                                          const __bf16* __restrict__ B,
                                          CT* __restrict__ C,
                                          int mb, int nb, int ldc, float scale,
                                          __bf16* As0, __bf16* As1,
                                          __bf16* Bs0, __bf16* Bs1,
                                          const float2* __restrict__ tbl) {
    int t = threadIdx.x;
    int w = t >> 6, l = t & 63;
    int wm = (w >> 1) * 64, wn = (w & 1) * 64;   // wave 2x2 grid, each 64x64
    int lrow = l & 15, lq = l >> 4;
    int cbr = (lq ^ (lrow & 3) ^ ((lrow >> 2) & 3)) * 8;  // read col (elems), kt-invariant
    f32x4 acc[4][4] = {};

    // staging: call c (0,1), lane l -> row c*64 + w*16 + (l>>2), col-block l&3.
    // LDS dest lane-linear (base + l*16B); global source col pre-swizzled.
    int srow = w * 16 + (l >> 2);
    int scb = ((l & 3) ^ ((l >> 2) & 3) ^ (l >> 4)) * 8;
    const __bf16* gA = A + (size_t)(mb * 128 + srow) * 1024 + scb;
    const __bf16* gB = B + (size_t)(nb * 128 + srow) * 1024 + scb;
    int lbase = (w * 16) * 32;                    // + c*64*32 (elems)

    auto stage = [&](int kt, __bf16* dA, __bf16* dB) {
        #pragma unroll
        for (int c = 0; c < 2; ++c) {
            GL2LDS(gA + (size_t)c * 64 * 1024 + kt * 32, dA + lbase + c * 64 * 32);
            GL2LDS(gB + (size_t)c * 64 * 1024 + kt * 32, dB + lbase + c * 64 * 32);
        }
    };
    auto step = [&](int kt, const __bf16* rA, const __bf16* rB,
                    __bf16* sA, __bf16* sB) {
        if (kt + 1 < 32) stage(kt + 1, sA, sB);   // DMA overlaps this step's MFMA
        bf16x8 af[4], bfr[4];
        #pragma unroll
        for (int i = 0; i < 4; ++i)
            af[i] = *(const bf16x8*)&rA[(wm + i * 16 + lrow) * 32 + cbr];
        #pragma unroll
        for (int i = 0; i < 4; ++i)
            bfr[i] = *(const bf16x8*)&rB[(wn + i * 16 + lrow) * 32 + cbr];
        #pragma unroll
        for (int rt = 0; rt < 4; ++rt)
            #pragma unroll
            for (int ct = 0; ct < 4; ++ct)
                acc[rt][ct] = MFMA16(af[rt], bfr[ct], acc[rt][ct]);
        __syncthreads();   // implicit vmcnt(0): next tile's DMA has landed
    };

    stage(0, As0, Bs0);
    __syncthreads();
    for (int kt = 0; kt < 32; kt += 2) {
        step(kt,     As0, Bs0, As1, Bs1);
        step(kt + 1, As1, Bs1, As0, Bs0);
    }

    #pragma unroll
    for (int rt = 0; rt < 4; ++rt)
        #pragma unroll
        for (int ct = 0; ct < 4; ++ct) {
            int colg = nb * 128 + wn + ct * 16 + lrow;
            int dp = ((ct * 16 + lrow) & 63) >> 1;   // pair index within head
            #pragma unroll
            for (int r = 0; r < 4; ++r) {
                int rowg = mb * 128 + wm + rt * 16 + lq * 4 + r;
                float v = acc[rt][ct][r] * scale;
                if constexpr (ROPE) {
                    float p = __shfl_xor(v, 1, 64);  // paired column, same row
                    float2 cs = tbl[((rowg & (NSEQ - 1)) << 5) + dp];
                    v = (lrow & 1) ? (v * cs.x + p * cs.y)   // odd col: x2 c + x1 s
                                   : (v * cs.x - p * cs.y);  // even col: x1 c - x2 s
                }
                C[(size_t)rowg * ldc + colg] = (CT)v;
            }
        }
}

// Fused QKV projections (+RoPE on q,k): grid (32, 8, 3) -> 768 blocks = 3/CU.
// Q scale folds BOTH 1/sqrt(64) AND log2(e): softmax runs in the exp2 domain.
__global__ __launch_bounds__(256) void qkv_kernel(const __bf16* __restrict__ x,
                                                  const __bf16* __restrict__ wq,
                                                  const __bf16* __restrict__ wk,
                                                  const __bf16* __restrict__ wv,
                                                  __bf16* __restrict__ qb,
                                                  __bf16* __restrict__ kb,
                                                  __bf16* __restrict__ vtb,
                                                  const float2* __restrict__ tbl) {
    __shared__ __bf16 As[2][128 * 32];
    __shared__ __bf16 Bs[2][128 * 32];
    int bm = blockIdx.x, bn = blockIdx.y, z = blockIdx.z;
    if (z == 0)      gemm_body<__bf16, true >(x,  wq, qb,  bm, bn, 1024,
                                       0.125f * 1.44269504088896340736f,
                                       As[0], As[1], Bs[0], Bs[1], tbl);
    else if (z == 1) gemm_body<__bf16, true >(x,  wk, kb,  bm, bn, 1024, 1.0f,
                                       As[0], As[1], Bs[0], Bs[1], tbl);
    else             gemm_body<__bf16, false>(wv, x,  vtb, bn, bm, 4096, 1.0f,
                                       As[0], As[1], Bs[0], Bs[1], tbl);
}

// Output projection, cvt ABSORBED: B is the fp32 wo weight, converted to bf16
// inline during staging (reg-stage B + write-side XOR swizzle; A stays GL2LDS).
// 128x64 tiles -> grid (32,16) = 2 blocks/CU.
__global__ __launch_bounds__(256) void wo_kernel(const __bf16* __restrict__ A,
                                                 const float* __restrict__ B,
                                                 float* __restrict__ C) {
    __shared__ __bf16 As[128 * 64];
    __shared__ __bf16 Bs[64 * 64];
    int mb = blockIdx.x, nb = blockIdx.y;
    int t = threadIdx.x;
    int w = t >> 6, l = t & 63;
    int wm = (w >> 1) * 64, wn = (w & 1) * 32;
    int lrow = l & 15, lq = l >> 4;
    int sw = lrow & 7;
    f32x4 acc[4][2] = {};

    int srowA = w * 32 + (l >> 3);       // A staging rows (4 calls x 8 rows)
    int sc8 = ((l & 7) ^ ((l >> 3) & 7)) * 8;    // A source pre-swizzle
    const __bf16* gA = A + (size_t)(mb * 128 + srowA) * 1024 + sc8;
    __bf16* lA = As + (size_t)(w * 32) * 64;

    // B fp32 staging: thread t -> row rB = t>>2 (64 rows), cols (t&3)*16..+15.
    int rB = t >> 2;
    const float* gB = B + (size_t)(nb * 64 + rB) * 1024 + (t & 3) * 16;
    int db0 = (rB * 8 + (((t & 3) * 2    ) ^ (rB & 7))) * 8;
    int db1 = (rB * 8 + (((t & 3) * 2 + 1) ^ (rB & 7))) * 8;

    for (int kt = 0; kt < 16; ++kt) {
        int k0 = kt * 64;
        #pragma unroll
        for (int c = 0; c < 4; ++c)
            GL2LDS(gA + (size_t)c * 8 * 1024 + k0, lA + c * 8 * 64);
        float4 b0 = *(const float4*)(gB + k0);
        float4 b1 = *(const float4*)(gB + k0 + 4);
        float4 b2 = *(const float4*)(gB + k0 + 8);
        float4 b3 = *(const float4*)(gB + k0 + 12);
        union { uint4 u; __bf16 h[8]; } p0, p1;
        p0.h[0] = (__bf16)b0.x; p0.h[1] = (__bf16)b0.y;
        p0.h[2] = (__bf16)b0.z; p0.h[3] = (__bf16)b0.w;
        p0.h[4] = (__bf16)b1.x; p0.h[5] = (__bf16)b1.y;
        p0.h[6] = (__bf16)b1.z; p0.h[7] = (__bf16)b1.w;
        p1.h[0] = (__bf16)b2.x; p1.h[1] = (__bf16)b2.y;
        p1.h[2] = (__bf16)b2.z; p1.h[3] = (__bf16)b2.w;
        p1.h[4] = (__bf16)b3.x; p1.h[5] = (__bf16)b3.y;
        p1.h[6] = (__bf16)b3.z; p1.h[7] = (__bf16)b3.w;
        *(uint4*)&Bs[db0] = p0.u;
        *(uint4*)&Bs[db1] = p1.u;
        __syncthreads();
        #pragma unroll
        for (int ch = 0; ch < 2; ++ch) {
            bf16x8 af[4], bfr[2];
            #pragma unroll
            for (int i = 0; i < 4; ++i)
                af[i] = *(const bf16x8*)&As[(wm + i * 16 + lrow) * 64 + ((ch * 4 + lq) ^ sw) * 8];
            #pragma unroll
            for (int i = 0; i < 2; ++i)
                bfr[i] = *(const bf16x8*)&Bs[(wn + i * 16 + lrow) * 64 + ((ch * 4 + lq) ^ sw) * 8];
            #pragma unroll
            for (int rt = 0; rt < 4; ++rt)
                #pragma unroll
                for (int ct = 0; ct < 2; ++ct)
                    acc[rt][ct] = MFMA16(af[rt], bfr[ct], acc[rt][ct]);
        }
        __syncthreads();
    }
    #pragma unroll
    for (int rt = 0; rt < 4; ++rt)
        #pragma unroll
        for (int ct = 0; ct < 2; ++ct)
            #pragma unroll
            for (int r = 0; r < 4; ++r) {
                int row = mb * 128 + wm + rt * 16 + lq * 4 + r;
                int col = nb * 64 + wn + ct * 16 + lrow;
                C[(size_t)row * 1024 + col] = acc[rt][ct][r];
            }
}

// ---------------- Causal flash attention v5d (unchanged from R9, passed) --------
__global__ __launch_bounds__(256, 3) void attn_kernel(const __bf16* __restrict__ q,
                                                      const __bf16* __restrict__ kk,
                                                      const __bf16* __restrict__ vt,
                                                      __bf16* __restrict__ o,
                                                      int* __restrict__ counters) {
    int xcd = blockIdx.x & 7;            // dispatch round-robins over XCDs
    int t = threadIdx.x;
    int w = t >> 6, l = t & 63;
    int lrow = l & 15, lq = l >> 4;
    int rw = (w & 1) * 32;               // wave's q-row offset within the item
    int par = w >> 1;                    // key-tile parity this wave handles
    int row0 = t >> 3;                   // staging row 0..31 (also +32)
    int cb = t & 7;                      // staging 16B col-block 0..7

    __shared__ __bf16 Kt[2][64 * 64];    // [parity][key][d], swizzled
    __shared__ __bf16 Vs[2][64 * 64];    // [parity][d][key], swizzled
    __shared__ __bf16 Ps[4][32 * 72];    // per-wave P^T strip; doubles as merge scratch
    __shared__ int s_item;
    __bf16* pw = Ps[w];

    int dsw0 = (row0 * 8 + (cb ^ (row0 & 7))) * 8;        // swizzled elem offset
    int dsw1 = ((row0 + 32) * 8 + (cb ^ (row0 & 7))) * 8; // (row0+32)&7 == row0&7

    if (t == 0) s_item = atomicAdd(&counters[xcd], 1);
    __syncthreads();
    int item = s_item;
    bool pf_valid = false;               // staged regs hold this item's tiles 0/1?
    uint4 k0a, k0b, v0a, v0b, k1a, k1b, v1a, v1b;

    while (item < 128) {
        int iq = 31 - (item >> 2);       // 64-row q-tile, long-first (LPT)
        int bh = xcd * 4 + (item & 3);   // 4 (b,h) pairs resident per XCD (L2)
        int h = bh & 15;
        int b = bh >> 4;
        int rowbase = b * NSEQ;

        const __bf16* kbase = kk + (size_t)rowbase * DIM + h * 64;
        const __bf16* vbase = vt + (size_t)(h * 64) * 4096 + b * 2048;
        const __bf16* kg = kbase + (size_t)row0 * DIM + cb * 8;
        const __bf16* vg = vbase + (size_t)row0 * 4096 + cb * 8;

        // Q fragments: 2 groups of 16 qrows (wave covers 32 rows)
        bf16x8 qf[2][2];
        #pragma unroll
        for (int g = 0; g < 2; ++g) {
            const __bf16* qp = q + (size_t)(rowbase + iq * 64 + rw + g * 16 + lrow) * DIM + h * 64;
            qf[g][0] = *(const bf16x8*)(qp + lq * 8);
            qf[g][1] = *(const bf16x8*)(qp + 32 + lq * 8);
        }

        f32x4 oacc[2][4] = {};           // O^T per group: [d-chunk], col = qrow
        float m_r[2] = {-1e30f, -1e30f};
        float l_r[2] = {0.0f, 0.0f};

        // prologue: tiles 0/1 (from merge-phase prefetch, or load now)
        if (!pf_valid) {
            k0a = *(const uint4*)(kg);
            k0b = *(const uint4*)(kg + (size_t)32 * DIM);
            v0a = *(const uint4*)(vg);
            v0b = *(const uint4*)(vg + (size_t)32 * 4096);
            if (iq >= 1) {
                k1a = *(const uint4*)(kg + (size_t)64 * DIM);
                k1b = *(const uint4*)(kg + (size_t)96 * DIM);
                v1a = *(const uint4*)(vg + 64);
                v1b = *(const uint4*)(vg + (size_t)32 * 4096 + 64);
            }
        }
        *(uint4*)&Kt[0][dsw0] = k0a; *(uint4*)&Kt[0][dsw1] = k0b;
        *(uint4*)&Vs[0][dsw0] = v0a; *(uint4*)&Vs[0][dsw1] = v0b;
        if (iq >= 1) {
            *(uint4*)&Kt[1][dsw0] = k1a; *(uint4*)&Kt[1][dsw1] = k1b;
            *(uint4*)&Vs[1][dsw0] = v1a; *(uint4*)&Vs[1][dsw1] = v1b;
        }
        __syncthreads();

        int R = (iq + 2) >> 1;           // rounds = ceil((iq+1)/2)
        for (int rd = 0; rd < R; ++rd) {
            if (rd == R - 1 && t == 0)   // early fetch of NEXT work item
                s_item = atomicAdd(&counters[xcd], 1);
            int jt = 2 * rd + par;       // this wave's key-tile
            bool pf = (rd + 1 < R);      // block-uniform
            if (pf) {                    // prefetch next round's tile pair
                int je = 2 * rd + 2;
                size_t ko = (size_t)je * 64 * DIM;
                k0a = *(const uint4*)(kg + ko);
                k0b = *(const uint4*)(kg + ko + (size_t)32 * DIM);
                v0a = *(const uint4*)(vg + je * 64);
                v0b = *(const uint4*)(vg + (size_t)32 * 4096 + je * 64);
                if (je + 1 <= iq) {
                    k1a = *(const uint4*)(kg + ko + (size_t)64 * DIM);
                    k1b = *(const uint4*)(kg + ko + (size_t)96 * DIM);
                    v1a = *(const uint4*)(vg + je * 64 + 64);
                    v1b = *(const uint4*)(vg + (size_t)32 * 4096 + je * 64 + 64);
                }
            }
            if (jt <= iq) {              // wave-uniform: inactive only in last round
                const __bf16* Kb = Kt[par];
                const __bf16* Vb = Vs[par];
                int sw = lrow & 7;
                // QK^T: K fragment read ONCE, used by both q-row groups
                f32x4 st[2][4];
                __builtin_amdgcn_s_setprio(1);
                #pragma unroll
                for (int ct = 0; ct < 4; ++ct) {
                    int rr = (ct * 16 + lrow) * 8;
                    bf16x8 ka0 = *(const bf16x8*)&Kb[(rr + (lq ^ sw)) * 8];
                    bf16x8 ka1 = *(const bf16x8*)&Kb[(rr + ((4 + lq) ^ sw)) * 8];
                    #pragma unroll
                    for (int g = 0; g < 2; ++g) {
                        f32x4 z = {};
                        z = MFMA16(ka0, qf[g][0], z);
                        z = MFMA16(ka1, qf[g][1], z);
                        st[g][ct] = z;   // key = ct*16+lq*4+r, qrow(local) = lrow
                    }
                }
                __builtin_amdgcn_s_setprio(0);
                if (jt == iq) {          // causal mask on diagonal tile
                    #pragma unroll
                    for (int g = 0; g < 2; ++g) {
                        int qrel = rw + g * 16 + lrow;
                        #pragma unroll
                        for (int ct = 0; ct < 4; ++ct)
                            #pragma unroll
                            for (int r = 0; r < 4; ++r)
                                if (ct * 16 + lq * 4 + r > qrel) st[g][ct][r] = -3.0e38f;
                    }
                }
                // online softmax (exp2 domain) per group
                #pragma unroll
                for (int g = 0; g < 2; ++g) {
                    float m0 = fmaxf(fmaxf(st[g][0][0], st[g][0][1]), fmaxf(st[g][0][2], st[g][0][3]));
                    float m1 = fmaxf(fmaxf(st[g][1][0], st[g][1][1]), fmaxf(st[g][1][2], st[g][1][3]));
                    float m2 = fmaxf(fmaxf(st[g][2][0], st[g][2][1]), fmaxf(st[g][2][2], st[g][2][3]));
                    float m3 = fmaxf(fmaxf(st[g][3][0], st[g][3][1]), fmaxf(st[g][3][2], st[g][3][3]));
                    float mx = fmaxf(fmaxf(m0, m1), fmaxf(m2, m3));
                    mx = fmaxf(mx, __shfl_xor(mx, 16, 64));
                    mx = fmaxf(mx, __shfl_xor(mx, 32, 64));
                    if (!__all(mx - m_r[g] <= 8.0f)) {   // defer-max (T13)
                        float mnew = fmaxf(m_r[g], mx);
                        float alpha = __builtin_amdgcn_exp2f(m_r[g] - mnew);
                        l_r[g] *= alpha;
                        #pragma unroll
                        for (int ct = 0; ct < 4; ++ct)
                            #pragma unroll
                            for (int r = 0; r < 4; ++r) oacc[g][ct][r] *= alpha;
                        m_r[g] = mnew;
                    }
                    float ps = 0.0f;
                    #pragma unroll
                    for (int ct = 0; ct < 4; ++ct)
                        #pragma unroll
                        for (int r = 0; r < 4; ++r) {
                            float p = __builtin_amdgcn_exp2f(st[g][ct][r] - m_r[g]);
                            st[g][ct][r] = p;
                            ps += p;
                        }
                    ps += __shfl_xor(ps, 16, 64);
                    ps += __shfl_xor(ps, 32, 64);
                    l_r[g] += ps;
                }
                // P^T -> per-wave strip (stride 72 = 16B-aligned rows)
                #pragma unroll
                for (int g = 0; g < 2; ++g)
                    #pragma unroll
                    for (int ct = 0; ct < 4; ++ct) {
                        union { uint2 u; __bf16 h4[4]; } pk;
                        #pragma unroll
                        for (int r = 0; r < 4; ++r) pk.h4[r] = (__bf16)st[g][ct][r];
                        *(uint2*)&pw[(g * 16 + lrow) * 72 + ct * 16 + lq * 4] = pk.u;
                    }
                bf16x8 pb[2][2];
                #pragma unroll
                for (int g = 0; g < 2; ++g) {
                    pb[g][0] = *(const bf16x8*)&pw[(g * 16 + lrow) * 72 + lq * 8];
                    pb[g][1] = *(const bf16x8*)&pw[(g * 16 + lrow) * 72 + 32 + lq * 8];
                }
                // O^T += V^T * P^T: V fragment read ONCE, used by both groups
                __builtin_amdgcn_s_setprio(1);
                #pragma unroll
                for (int ct = 0; ct < 4; ++ct) {
                    int rr = (ct * 16 + lrow) * 8;
                    bf16x8 va0 = *(const bf16x8*)&Vb[(rr + (lq ^ sw)) * 8];
                    bf16x8 va1 = *(const bf16x8*)&Vb[(rr + ((4 + lq) ^ sw)) * 8];
                    #pragma unroll
                    for (int g = 0; g < 2; ++g) {
                        oacc[g][ct] = MFMA16(va0, pb[g][0], oacc[g][ct]);
                        oacc[g][ct] = MFMA16(va1, pb[g][1], oacc[g][ct]);
                    }
                }
                __builtin_amdgcn_s_setprio(0);
            }
            if (pf) {                    // publish next round's tiles
                __syncthreads();         // everyone done reading bufs
                *(uint4*)&Kt[0][dsw0] = k0a; *(uint4*)&Kt[0][dsw1] = k0b;
                *(uint4*)&Vs[0][dsw0] = v0a; *(uint4*)&Vs[0][dsw1] = v0b;
                if (2 * rd + 3 <= iq) {
                    *(uint4*)&Kt[1][dsw0] = k1a; *(uint4*)&Kt[1][dsw1] = k1b;
                    *(uint4*)&Vs[1][dsw0] = v1a; *(uint4*)&Vs[1][dsw1] = v1b;
                }
                __syncthreads();
            }
        }

        // ---- merge parity partials + store; overlap next item's tile loads -----
        __syncthreads();                 // all compute done; s_item (early fetch)
                                         // now visible; scratch (aliases Ps) safe
        int nitem = s_item;
        if (nitem < 128) {               // prefetch next item's tiles 0/1 (regs free)
            int niq = 31 - (nitem >> 2);
            int nbh = xcd * 4 + (nitem & 3);
            int nh = nbh & 15;
            int nb_ = nbh >> 4;
            const __bf16* nkg = kk + ((size_t)(nb_ * NSEQ) + row0) * DIM + nh * 64 + cb * 8;
            const __bf16* nvg = vt + (size_t)(nh * 64 + row0) * 4096 + nb_ * 2048 + cb * 8;
            k0a = *(const uint4*)(nkg);
            k0b = *(const uint4*)(nkg + (size_t)32 * DIM);
            v0a = *(const uint4*)(nvg);
            v0b = *(const uint4*)(nvg + (size_t)32 * 4096);
            if (niq >= 1) {
                k1a = *(const uint4*)(nkg + (size_t)64 * DIM);
                k1b = *(const uint4*)(nkg + (size_t)96 * DIM);
                v1a = *(const uint4*)(nvg + 64);
                v1b = *(const uint4*)(nvg + (size_t)32 * 4096 + 64);
            }
        }
        float* sc = (float*)&Ps[0][0];               // 18432 B = 2 x 64 x 36 floats
        float* base = sc + (w & 1) * 2304 + l * 36;
        if (par == 1) {
            #pragma unroll
            for (int g = 0; g < 2; ++g)
                #pragma unroll
                for (int ct = 0; ct < 4; ++ct)
                    *(f32x4*)(base + g * 16 + ct * 4) = oacc[g][ct];
            base[32] = m_r[0]; base[33] = m_r[1];
            base[34] = l_r[0]; base[35] = l_r[1];
        }
        __syncthreads();
        if (par == 0) {
            #pragma unroll
            for (int g = 0; g < 2; ++g) {
                float mb = base[32 + g], lb = base[34 + g];
                float m = fmaxf(m_r[g], mb);
                float a  = __builtin_amdgcn_exp2f(m_r[g] - m);
                float bb = __builtin_amdgcn_exp2f(mb - m);
                float rcp = 1.0f / (a * l_r[g] + bb * lb);
                const size_t orow = (size_t)(rowbase + iq * 64 + rw + g * 16 + lrow) * DIM + h * 64;
                #pragma unroll
                for (int ct = 0; ct < 4; ++ct) {
                    f32x4 ob = *(const f32x4*)(base + g * 16 + ct * 4);
                    union { uint2 u; __bf16 h4[4]; } pk;
                    #pragma unroll
                    for (int r = 0; r < 4; ++r)
                        pk.h4[r] = (__bf16)((a * oacc[g][ct][r] + bb * ob[r]) * rcp);
                    *(uint2*)(o + orow + ct * 16 + lq * 4) = pk.u;
                }
            }
        }
        item = nitem;
        pf_valid = true;
        // no loop-top barrier needed: par0's scratch reads precede its own staging
        // in program order; other waves' first P write is behind the prologue
        // barrier; Kt/Vs staging doesn't alias the Ps scratch.
    }
}

extern "C" void kernel_launch(void* const* d_in, const int* in_sizes, int n_in,
                              void* d_out, int out_size, void* d_ws, size_t ws_size,
                              hipStream_t stream) {
    const float* tokens = (const float*)d_in[0];
    const float* gamma  = (const float*)d_in[1];
    const float* wq = (const float*)d_in[2];
    const float* wk = (const float*)d_in[3];
    const float* wv = (const float*)d_in[4];
    const float* wo = (const float*)d_in[5];

    __bf16* ws  = (__bf16*)d_ws;
    __bf16* x   = ws;                           // 4096*1024
    __bf16* qb  = x   + (size_t)4096 * 1024;
    __bf16* kb  = qb  + (size_t)4096 * 1024;
    __bf16* vtb = kb  + (size_t)4096 * 1024;    // V^T: 1024 x 4096
    __bf16* ao  = x;                            // alias: attn out reuses x's buffer
    float*  out = (float*)d_out;

    // d_out scratch layout (all dead before wo_kernel writes C):
    // [0,6MB): bf16 wq/wk/wv; [6MB,6.5MB): rope cos/sin table; [8MB): counters.
    __bf16* wqb = (__bf16*)d_out;
    __bf16* wkb = wqb + (size_t)1024 * 1024;
    __bf16* wvb = wkb + (size_t)1024 * 1024;
    float2* tbl = (float2*)((char*)d_out + (size_t)6 * 1024 * 1024);
    int* counters = (int*)((char*)d_out + (size_t)8 * 1024 * 1024);

    pre_kernel<<<7424, 256, 0, stream>>>(wq, wk, wv, wqb, wkb, wvb, tbl, counters,
                                         tokens, gamma, x);

    qkv_kernel<<<dim3(32, 8, 3), 256, 0, stream>>>(x, wqb, wkb, wvb, qb, kb, vtb, tbl);

    attn_kernel<<<768, 256, 0, stream>>>(qb, kb, vtb, ao, counters);

    wo_kernel<<<dim3(32, 16), 256, 0, stream>>>(ao, wo, out);
}

// Round 11
// 202.434 us; speedup vs baseline: 1.0204x; 1.0204x over previous
//
#include <hip/hip_runtime.h>

typedef __bf16 bf16x8 __attribute__((ext_vector_type(8)));
typedef float f32x4 __attribute__((ext_vector_type(4)));

#define DIM 1024
#define NSEQ 2048

// async 16B global -> LDS DMA (lane-linear: wave-uniform LDS base + lane*16)
#define GL2LDS(g, l) __builtin_amdgcn_global_load_lds( \
    (const __attribute__((address_space(1))) void*)(g), \
    (__attribute__((address_space(3))) void*)(l), 16, 0, 0)

#define MFMA16(a, b, c) __builtin_amdgcn_mfma_f32_16x16x32_bf16(a, b, c, 0, 0, 0)

// ---------------- fused pre-pass: cvt wq/wk/wv + rope cos/sin table + rmsnorm ---
__global__ __launch_bounds__(256) void pre_kernel(const float* __restrict__ wq,
                                                  const float* __restrict__ wk,
                                                  const float* __restrict__ wv,
                                                  __bf16* __restrict__ dq,
                                                  __bf16* __restrict__ dk,
                                                  __bf16* __restrict__ dv,
                                                  float2* __restrict__ tbl,
                                                  int* __restrict__ counters,
                                                  const float* __restrict__ x,
                                                  const float* __restrict__ g,
                                                  __bf16* __restrict__ xo) {
    int bid = blockIdx.x;
    int t = threadIdx.x;
    if (bid == 0 && t < 8) counters[t] = 0;
    if (bid < 3072) {                    // weight conversion
        int slice = bid >> 10;
        const float* s = slice == 0 ? wq : (slice == 1 ? wk : wv);
        __bf16*      d = slice == 0 ? dq : (slice == 1 ? dk : dv);
        int i = ((bid & 1023) * 256 + t) * 4;
        float4 f = *(const float4*)(s + i);
        union { uint2 u; __bf16 h[4]; } p;
        p.h[0] = (__bf16)f.x; p.h[1] = (__bf16)f.y;
        p.h[2] = (__bf16)f.z; p.h[3] = (__bf16)f.w;
        *(uint2*)(d + i) = p.u;
    } else if (bid < 3328) {             // rope table: tbl[pos*32+dp] = {cos,sin}
        int e = (bid - 3072) * 256 + t;
        int pos = e >> 5, dp = e & 31;
        float inv = __expf(-(float)dp * (9.210340371976184f / 32.0f));
        float sn, cs;
        sincosf((float)pos * inv, &sn, &cs);
        tbl[e] = make_float2(cs, sn);
    } else {                             // RMSNorm row
        int row = bid - 3328;
        float4 xv = ((const float4*)(x + (size_t)row * DIM))[t];
        float ss = xv.x*xv.x + xv.y*xv.y + xv.z*xv.z + xv.w*xv.w;
        #pragma unroll
        for (int off = 32; off; off >>= 1) ss += __shfl_xor(ss, off, 64);
        __shared__ float red[4];
        if ((t & 63) == 0) red[t >> 6] = ss;
        __syncthreads();
        ss = red[0] + red[1] + red[2] + red[3];
        float r = rsqrtf(ss * (1.0f / 1024.0f) + 1.1920929e-07f);
        float4 gv = ((const float4*)g)[t];
        union { uint2 u; __bf16 h[4]; } p;
        p.h[0] = (__bf16)(xv.x * r * gv.x);
        p.h[1] = (__bf16)(xv.y * r * gv.y);
        p.h[2] = (__bf16)(xv.z * r * gv.z);
        p.h[3] = (__bf16)(xv.w * r * gv.w);
        *(uint2*)(xo + (size_t)row * DIM + t * 4) = p.u;
    }
}

// ---------------- shared GEMM body (EXACT R8 revert): BK=64, single buffer ------
// R10 pm: BK=32 2-phase regressed (64B rows can't be made conflict-free: only 4
// col-blocks for 8 aliasing rows -> 3.1M conflicts; 2x barriers). This is the
// best-measured structure (R8: qkv < 50us). T2 swizzle: GL2LDS lane-linear dest,
// global SOURCE pre-swizzled (lane l fetches col-block (l&7)^((l>>3)&7)) so
// LDS[row][cb] = G[row][cb^(row&7)]; readers XOR with lrow&7.
template <typename CT, bool ROPE>
__device__ __forceinline__ void gemm_body(const __bf16* __restrict__ A,
                                          const __bf16* __restrict__ B,
                                          CT* __restrict__ C,
                                          int mb, int nb, int ldc, float scale,
                                          __bf16* As, __bf16* Bs,
                                          const float2* __restrict__ tbl) {
    int t = threadIdx.x;
    int w = t >> 6, l = t & 63;
    int wm = (w >> 1) * 64, wn = (w & 1) * 64;   // wave 2x2 grid, each 64x64
    int lrow = l & 15, lq = l >> 4;
    int sw = lrow & 7;                           // read-side XOR key
    f32x4 acc[4][4] = {};

    int srow = w * 32 + (l >> 3);
    int sc8 = ((l & 7) ^ ((l >> 3) & 7)) * 8;    // source pre-swizzle
    const __bf16* gA = A + (size_t)(mb * 128 + srow) * 1024 + sc8;
    const __bf16* gB = B + (size_t)(nb * 128 + srow) * 1024 + sc8;
    __bf16* lA = As + (size_t)(w * 32) * 64;     // + c*8*64
    __bf16* lB = Bs + (size_t)(w * 32) * 64;

    for (int kt = 0; kt < 16; ++kt) {
        int k0 = kt * 64;
        #pragma unroll
        for (int c = 0; c < 4; ++c) {
            GL2LDS(gA + (size_t)c * 8 * 1024 + k0, lA + c * 8 * 64);
            GL2LDS(gB + (size_t)c * 8 * 1024 + k0, lB + c * 8 * 64);
        }
        __syncthreads();    // drains DMA, publishes tile
        #pragma unroll
        for (int ch = 0; ch < 2; ++ch) {
            bf16x8 af[4], bfr[4];
            #pragma unroll
            for (int i = 0; i < 4; ++i)
                af[i] = *(const bf16x8*)&As[(wm + i * 16 + lrow) * 64 + ((ch * 4 + lq) ^ sw) * 8];
            #pragma unroll
            for (int i = 0; i < 4; ++i)
                bfr[i] = *(const bf16x8*)&Bs[(wn + i * 16 + lrow) * 64 + ((ch * 4 + lq) ^ sw) * 8];
            #pragma unroll
            for (int rt = 0; rt < 4; ++rt)
                #pragma unroll
                for (int ct = 0; ct < 4; ++ct)
                    acc[rt][ct] = MFMA16(af[rt], bfr[ct], acc[rt][ct]);
        }
        __syncthreads();
    }
    #pragma unroll
    for (int rt = 0; rt < 4; ++rt)
        #pragma unroll
        for (int ct = 0; ct < 4; ++ct) {
            int colg = nb * 128 + wn + ct * 16 + lrow;
            int dp = ((ct * 16 + lrow) & 63) >> 1;   // pair index within head
            #pragma unroll
            for (int r = 0; r < 4; ++r) {
                int rowg = mb * 128 + wm + rt * 16 + lq * 4 + r;
                float v = acc[rt][ct][r] * scale;
                if constexpr (ROPE) {
                    float p = __shfl_xor(v, 1, 64);  // paired column, same row
                    float2 cs = tbl[((rowg & (NSEQ - 1)) << 5) + dp];
                    v = (lrow & 1) ? (v * cs.x + p * cs.y)   // odd col: x2 c + x1 s
                                   : (v * cs.x - p * cs.y);  // even col: x1 c - x2 s
                }
                C[(size_t)rowg * ldc + colg] = (CT)v;
            }
        }
}

// Fused QKV projections (+RoPE on q,k): grid (32, 8, 3) -> 768 blocks = 3/CU.
// Q scale folds BOTH 1/sqrt(64) AND log2(e): softmax runs in the exp2 domain.
__global__ __launch_bounds__(256) void qkv_kernel(const __bf16* __restrict__ x,
                                                  const __bf16* __restrict__ wq,
                                                  const __bf16* __restrict__ wk,
                                                  const __bf16* __restrict__ wv,
                                                  __bf16* __restrict__ qb,
                                                  __bf16* __restrict__ kb,
                                                  __bf16* __restrict__ vtb,
                                                  const float2* __restrict__ tbl) {
    __shared__ __bf16 As[128 * 64];
    __shared__ __bf16 Bs[128 * 64];
    int bm = blockIdx.x, bn = blockIdx.y, z = blockIdx.z;
    if (z == 0)      gemm_body<__bf16, true >(x,  wq, qb,  bm, bn, 1024,
                                       0.125f * 1.44269504088896340736f, As, Bs, tbl);
    else if (z == 1) gemm_body<__bf16, true >(x,  wk, kb,  bm, bn, 1024, 1.0f, As, Bs, tbl);
    else             gemm_body<__bf16, false>(wv, x,  vtb, bn, bm, 4096, 1.0f, As, Bs, tbl);
}

// Output projection, cvt ABSORBED: B is the fp32 wo weight, converted to bf16
// inline during staging (reg-stage B + write-side XOR swizzle; A stays GL2LDS).
// 128x64 tiles -> grid (32,16) = 2 blocks/CU.
__global__ __launch_bounds__(256) void wo_kernel(const __bf16* __restrict__ A,
                                                 const float* __restrict__ B,
                                                 float* __restrict__ C) {
    __shared__ __bf16 As[128 * 64];
    __shared__ __bf16 Bs[64 * 64];
    int mb = blockIdx.x, nb = blockIdx.y;
    int t = threadIdx.x;
    int w = t >> 6, l = t & 63;
    int wm = (w >> 1) * 64, wn = (w & 1) * 32;
    int lrow = l & 15, lq = l >> 4;
    int sw = lrow & 7;
    f32x4 acc[4][2] = {};

    int srowA = w * 32 + (l >> 3);       // A staging rows (4 calls x 8 rows)
    int sc8 = ((l & 7) ^ ((l >> 3) & 7)) * 8;    // A source pre-swizzle
    const __bf16* gA = A + (size_t)(mb * 128 + srowA) * 1024 + sc8;
    __bf16* lA = As + (size_t)(w * 32) * 64;

    // B fp32 staging: thread t -> row rB = t>>2 (64 rows), cols (t&3)*16..+15.
    int rB = t >> 2;
    const float* gB = B + (size_t)(nb * 64 + rB) * 1024 + (t & 3) * 16;
    int db0 = (rB * 8 + (((t & 3) * 2    ) ^ (rB & 7))) * 8;
    int db1 = (rB * 8 + (((t & 3) * 2 + 1) ^ (rB & 7))) * 8;

    for (int kt = 0; kt < 16; ++kt) {
        int k0 = kt * 64;
        #pragma unroll
        for (int c = 0; c < 4; ++c)
            GL2LDS(gA + (size_t)c * 8 * 1024 + k0, lA + c * 8 * 64);
        float4 b0 = *(const float4*)(gB + k0);
        float4 b1 = *(const float4*)(gB + k0 + 4);
        float4 b2 = *(const float4*)(gB + k0 + 8);
        float4 b3 = *(const float4*)(gB + k0 + 12);
        union { uint4 u; __bf16 h[8]; } p0, p1;
        p0.h[0] = (__bf16)b0.x; p0.h[1] = (__bf16)b0.y;
        p0.h[2] = (__bf16)b0.z; p0.h[3] = (__bf16)b0.w;
        p0.h[4] = (__bf16)b1.x; p0.h[5] = (__bf16)b1.y;
        p0.h[6] = (__bf16)b1.z; p0.h[7] = (__bf16)b1.w;
        p1.h[0] = (__bf16)b2.x; p1.h[1] = (__bf16)b2.y;
        p1.h[2] = (__bf16)b2.z; p1.h[3] = (__bf16)b2.w;
        p1.h[4] = (__bf16)b3.x; p1.h[5] = (__bf16)b3.y;
        p1.h[6] = (__bf16)b3.z; p1.h[7] = (__bf16)b3.w;
        *(uint4*)&Bs[db0] = p0.u;
        *(uint4*)&Bs[db1] = p1.u;
        __syncthreads();
        #pragma unroll
        for (int ch = 0; ch < 2; ++ch) {
            bf16x8 af[4], bfr[2];
            #pragma unroll
            for (int i = 0; i < 4; ++i)
                af[i] = *(const bf16x8*)&As[(wm + i * 16 + lrow) * 64 + ((ch * 4 + lq) ^ sw) * 8];
            #pragma unroll
            for (int i = 0; i < 2; ++i)
                bfr[i] = *(const bf16x8*)&Bs[(wn + i * 16 + lrow) * 64 + ((ch * 4 + lq) ^ sw) * 8];
            #pragma unroll
            for (int rt = 0; rt < 4; ++rt)
                #pragma unroll
                for (int ct = 0; ct < 2; ++ct)
                    acc[rt][ct] = MFMA16(af[rt], bfr[ct], acc[rt][ct]);
        }
        __syncthreads();
    }
    #pragma unroll
    for (int rt = 0; rt < 4; ++rt)
        #pragma unroll
        for (int ct = 0; ct < 2; ++ct)
            #pragma unroll
            for (int r = 0; r < 4; ++r) {
                int row = mb * 128 + wm + rt * 16 + lq * 4 + r;
                int col = nb * 64 + wn + ct * 16 + lrow;
                C[(size_t)row * 1024 + col] = acc[rt][ct][r];
            }
}

// ---------------- Causal flash attention v5d (unchanged, passed twice) ----------
__global__ __launch_bounds__(256, 3) void attn_kernel(const __bf16* __restrict__ q,
                                                      const __bf16* __restrict__ kk,
                                                      const __bf16* __restrict__ vt,
                                                      __bf16* __restrict__ o,
                                                      int* __restrict__ counters) {
    int xcd = blockIdx.x & 7;            // dispatch round-robins over XCDs
    int t = threadIdx.x;
    int w = t >> 6, l = t & 63;
    int lrow = l & 15, lq = l >> 4;
    int rw = (w & 1) * 32;               // wave's q-row offset within the item
    int par = w >> 1;                    // key-tile parity this wave handles
    int row0 = t >> 3;                   // staging row 0..31 (also +32)
    int cb = t & 7;                      // staging 16B col-block 0..7

    __shared__ __bf16 Kt[2][64 * 64];    // [parity][key][d], swizzled
    __shared__ __bf16 Vs[2][64 * 64];    // [parity][d][key], swizzled
    __shared__ __bf16 Ps[4][32 * 72];    // per-wave P^T strip; doubles as merge scratch
    __shared__ int s_item;
    __bf16* pw = Ps[w];

    int dsw0 = (row0 * 8 + (cb ^ (row0 & 7))) * 8;        // swizzled elem offset
    int dsw1 = ((row0 + 32) * 8 + (cb ^ (row0 & 7))) * 8; // (row0+32)&7 == row0&7

    if (t == 0) s_item = atomicAdd(&counters[xcd], 1);
    __syncthreads();
    int item = s_item;
    bool pf_valid = false;               // staged regs hold this item's tiles 0/1?
    uint4 k0a, k0b, v0a, v0b, k1a, k1b, v1a, v1b;

    while (item < 128) {
        int iq = 31 - (item >> 2);       // 64-row q-tile, long-first (LPT)
        int bh = xcd * 4 + (item & 3);   // 4 (b,h) pairs resident per XCD (L2)
        int h = bh & 15;
        int b = bh >> 4;
        int rowbase = b * NSEQ;

        const __bf16* kbase = kk + (size_t)rowbase * DIM + h * 64;
        const __bf16* vbase = vt + (size_t)(h * 64) * 4096 + b * 2048;
        const __bf16* kg = kbase + (size_t)row0 * DIM + cb * 8;
        const __bf16* vg = vbase + (size_t)row0 * 4096 + cb * 8;

        // Q fragments: 2 groups of 16 qrows (wave covers 32 rows)
        bf16x8 qf[2][2];
        #pragma unroll
        for (int g = 0; g < 2; ++g) {
            const __bf16* qp = q + (size_t)(rowbase + iq * 64 + rw + g * 16 + lrow) * DIM + h * 64;
            qf[g][0] = *(const bf16x8*)(qp + lq * 8);
            qf[g][1] = *(const bf16x8*)(qp + 32 + lq * 8);
        }

        f32x4 oacc[2][4] = {};           // O^T per group: [d-chunk], col = qrow
        float m_r[2] = {-1e30f, -1e30f};
        float l_r[2] = {0.0f, 0.0f};

        // prologue: tiles 0/1 (from merge-phase prefetch, or load now)
        if (!pf_valid) {
            k0a = *(const uint4*)(kg);
            k0b = *(const uint4*)(kg + (size_t)32 * DIM);
            v0a = *(const uint4*)(vg);
            v0b = *(const uint4*)(vg + (size_t)32 * 4096);
            if (iq >= 1) {
                k1a = *(const uint4*)(kg + (size_t)64 * DIM);
                k1b = *(const uint4*)(kg + (size_t)96 * DIM);
                v1a = *(const uint4*)(vg + 64);
                v1b = *(const uint4*)(vg + (size_t)32 * 4096 + 64);
            }
        }
        *(uint4*)&Kt[0][dsw0] = k0a; *(uint4*)&Kt[0][dsw1] = k0b;
        *(uint4*)&Vs[0][dsw0] = v0a; *(uint4*)&Vs[0][dsw1] = v0b;
        if (iq >= 1) {
            *(uint4*)&Kt[1][dsw0] = k1a; *(uint4*)&Kt[1][dsw1] = k1b;
            *(uint4*)&Vs[1][dsw0] = v1a; *(uint4*)&Vs[1][dsw1] = v1b;
        }
        __syncthreads();

        int R = (iq + 2) >> 1;           // rounds = ceil((iq+1)/2)
        for (int rd = 0; rd < R; ++rd) {
            if (rd == R - 1 && t == 0)   // early fetch of NEXT work item
                s_item = atomicAdd(&counters[xcd], 1);
            int jt = 2 * rd + par;       // this wave's key-tile
            bool pf = (rd + 1 < R);      // block-uniform
            if (pf) {                    // prefetch next round's tile pair
                int je = 2 * rd + 2;
                size_t ko = (size_t)je * 64 * DIM;
                k0a = *(const uint4*)(kg + ko);
                k0b = *(const uint4*)(kg + ko + (size_t)32 * DIM);
                v0a = *(const uint4*)(vg + je * 64);
                v0b = *(const uint4*)(vg + (size_t)32 * 4096 + je * 64);
                if (je + 1 <= iq) {
                    k1a = *(const uint4*)(kg + ko + (size_t)64 * DIM);
                    k1b = *(const uint4*)(kg + ko + (size_t)96 * DIM);
                    v1a = *(const uint4*)(vg + je * 64 + 64);
                    v1b = *(const uint4*)(vg + (size_t)32 * 4096 + je * 64 + 64);
                }
            }
            if (jt <= iq) {              // wave-uniform: inactive only in last round
                const __bf16* Kb = Kt[par];
                const __bf16* Vb = Vs[par];
                int sw = lrow & 7;
                // QK^T: K fragment read ONCE, used by both q-row groups
                f32x4 st[2][4];
                __builtin_amdgcn_s_setprio(1);
                #pragma unroll
                for (int ct = 0; ct < 4; ++ct) {
                    int rr = (ct * 16 + lrow) * 8;
                    bf16x8 ka0 = *(const bf16x8*)&Kb[(rr + (lq ^ sw)) * 8];
                    bf16x8 ka1 = *(const bf16x8*)&Kb[(rr + ((4 + lq) ^ sw)) * 8];
                    #pragma unroll
                    for (int g = 0; g < 2; ++g) {
                        f32x4 z = {};
                        z = MFMA16(ka0, qf[g][0], z);
                        z = MFMA16(ka1, qf[g][1], z);
                        st[g][ct] = z;   // key = ct*16+lq*4+r, qrow(local) = lrow
                    }
                }
                __builtin_amdgcn_s_setprio(0);
                if (jt == iq) {          // causal mask on diagonal tile
                    #pragma unroll
                    for (int g = 0; g < 2; ++g) {
                        int qrel = rw + g * 16 + lrow;
                        #pragma unroll
                        for (int ct = 0; ct < 4; ++ct)
                            #pragma unroll
                            for (int r = 0; r < 4; ++r)
                                if (ct * 16 + lq * 4 + r > qrel) st[g][ct][r] = -3.0e38f;
                    }
                }
                // online softmax (exp2 domain) per group
                #pragma unroll
                for (int g = 0; g < 2; ++g) {
                    float m0 = fmaxf(fmaxf(st[g][0][0], st[g][0][1]), fmaxf(st[g][0][2], st[g][0][3]));
                    float m1 = fmaxf(fmaxf(st[g][1][0], st[g][1][1]), fmaxf(st[g][1][2], st[g][1][3]));
                    float m2 = fmaxf(fmaxf(st[g][2][0], st[g][2][1]), fmaxf(st[g][2][2], st[g][2][3]));
                    float m3 = fmaxf(fmaxf(st[g][3][0], st[g][3][1]), fmaxf(st[g][3][2], st[g][3][3]));
                    float mx = fmaxf(fmaxf(m0, m1), fmaxf(m2, m3));
                    mx = fmaxf(mx, __shfl_xor(mx, 16, 64));
                    mx = fmaxf(mx, __shfl_xor(mx, 32, 64));
                    if (!__all(mx - m_r[g] <= 8.0f)) {   // defer-max (T13)
                        float mnew = fmaxf(m_r[g], mx);
                        float alpha = __builtin_amdgcn_exp2f(m_r[g] - mnew);
                        l_r[g] *= alpha;
                        #pragma unroll
                        for (int ct = 0; ct < 4; ++ct)
                            #pragma unroll
                            for (int r = 0; r < 4; ++r) oacc[g][ct][r] *= alpha;
                        m_r[g] = mnew;
                    }
                    float ps = 0.0f;
                    #pragma unroll
                    for (int ct = 0; ct < 4; ++ct)
                        #pragma unroll
                        for (int r = 0; r < 4; ++r) {
                            float p = __builtin_amdgcn_exp2f(st[g][ct][r] - m_r[g]);
                            st[g][ct][r] = p;
                            ps += p;
                        }
                    ps += __shfl_xor(ps, 16, 64);
                    ps += __shfl_xor(ps, 32, 64);
                    l_r[g] += ps;
                }
                // P^T -> per-wave strip (stride 72 = 16B-aligned rows)
                #pragma unroll
                for (int g = 0; g < 2; ++g)
                    #pragma unroll
                    for (int ct = 0; ct < 4; ++ct) {
                        union { uint2 u; __bf16 h4[4]; } pk;
                        #pragma unroll
                        for (int r = 0; r < 4; ++r) pk.h4[r] = (__bf16)st[g][ct][r];
                        *(uint2*)&pw[(g * 16 + lrow) * 72 + ct * 16 + lq * 4] = pk.u;
                    }
                bf16x8 pb[2][2];
                #pragma unroll
                for (int g = 0; g < 2; ++g) {
                    pb[g][0] = *(const bf16x8*)&pw[(g * 16 + lrow) * 72 + lq * 8];
                    pb[g][1] = *(const bf16x8*)&pw[(g * 16 + lrow) * 72 + 32 + lq * 8];
                }
                // O^T += V^T * P^T: V fragment read ONCE, used by both groups
                __builtin_amdgcn_s_setprio(1);
                #pragma unroll
                for (int ct = 0; ct < 4; ++ct) {
                    int rr = (ct * 16 + lrow) * 8;
                    bf16x8 va0 = *(const bf16x8*)&Vb[(rr + (lq ^ sw)) * 8];
                    bf16x8 va1 = *(const bf16x8*)&Vb[(rr + ((4 + lq) ^ sw)) * 8];
                    #pragma unroll
                    for (int g = 0; g < 2; ++g) {
                        oacc[g][ct] = MFMA16(va0, pb[g][0], oacc[g][ct]);
                        oacc[g][ct] = MFMA16(va1, pb[g][1], oacc[g][ct]);
                    }
                }
                __builtin_amdgcn_s_setprio(0);
            }
            if (pf) {                    // publish next round's tiles
                __syncthreads();         // everyone done reading bufs
                *(uint4*)&Kt[0][dsw0] = k0a; *(uint4*)&Kt[0][dsw1] = k0b;
                *(uint4*)&Vs[0][dsw0] = v0a; *(uint4*)&Vs[0][dsw1] = v0b;
                if (2 * rd + 3 <= iq) {
                    *(uint4*)&Kt[1][dsw0] = k1a; *(uint4*)&Kt[1][dsw1] = k1b;
                    *(uint4*)&Vs[1][dsw0] = v1a; *(uint4*)&Vs[1][dsw1] = v1b;
                }
                __syncthreads();
            }
        }

        // ---- merge parity partials + store; overlap next item's tile loads -----
        __syncthreads();                 // all compute done; s_item (early fetch)
                                         // now visible; scratch (aliases Ps) safe
        int nitem = s_item;
        if (nitem < 128) {               // prefetch next item's tiles 0/1 (regs free)
            int niq = 31 - (nitem >> 2);
            int nbh = xcd * 4 + (nitem & 3);
            int nh = nbh & 15;
            int nb_ = nbh >> 4;
            const __bf16* nkg = kk + ((size_t)(nb_ * NSEQ) + row0) * DIM + nh * 64 + cb * 8;
            const __bf16* nvg = vt + (size_t)(nh * 64 + row0) * 4096 + nb_ * 2048 + cb * 8;
            k0a = *(const uint4*)(nkg);
            k0b = *(const uint4*)(nkg + (size_t)32 * DIM);
            v0a = *(const uint4*)(nvg);
            v0b = *(const uint4*)(nvg + (size_t)32 * 4096);
            if (niq >= 1) {
                k1a = *(const uint4*)(nkg + (size_t)64 * DIM);
                k1b = *(const uint4*)(nkg + (size_t)96 * DIM);
                v1a = *(const uint4*)(nvg + 64);
                v1b = *(const uint4*)(nvg + (size_t)32 * 4096 + 64);
            }
        }
        float* sc = (float*)&Ps[0][0];               // 18432 B = 2 x 64 x 36 floats
        float* base = sc + (w & 1) * 2304 + l * 36;
        if (par == 1) {
            #pragma unroll
            for (int g = 0; g < 2; ++g)
                #pragma unroll
                for (int ct = 0; ct < 4; ++ct)
                    *(f32x4*)(base + g * 16 + ct * 4) = oacc[g][ct];
            base[32] = m_r[0]; base[33] = m_r[1];
            base[34] = l_r[0]; base[35] = l_r[1];
        }
        __syncthreads();
        if (par == 0) {
            #pragma unroll
            for (int g = 0; g < 2; ++g) {
                float mb = base[32 + g], lb = base[34 + g];
                float m = fmaxf(m_r[g], mb);
                float a  = __builtin_amdgcn_exp2f(m_r[g] - m);
                float bb = __builtin_amdgcn_exp2f(mb - m);
                float rcp = 1.0f / (a * l_r[g] + bb * lb);
                const size_t orow = (size_t)(rowbase + iq * 64 + rw + g * 16 + lrow) * DIM + h * 64;
                #pragma unroll
                for (int ct = 0; ct < 4; ++ct) {
                    f32x4 ob = *(const f32x4*)(base + g * 16 + ct * 4);
                    union { uint2 u; __bf16 h4[4]; } pk;
                    #pragma unroll
                    for (int r = 0; r < 4; ++r)
                        pk.h4[r] = (__bf16)((a * oacc[g][ct][r] + bb * ob[r]) * rcp);
                    *(uint2*)(o + orow + ct * 16 + lq * 4) = pk.u;
                }
            }
        }
        item = nitem;
        pf_valid = true;
        // no loop-top barrier needed: par0's scratch reads precede its own staging
        // in program order; other waves' first P write is behind the prologue
        // barrier; Kt/Vs staging doesn't alias the Ps scratch.
    }
}

extern "C" void kernel_launch(void* const* d_in, const int* in_sizes, int n_in,
                              void* d_out, int out_size, void* d_ws, size_t ws_size,
                              hipStream_t stream) {
    const float* tokens = (const float*)d_in[0];
    const float* gamma  = (const float*)d_in[1];
    const float* wq = (const float*)d_in[2];
    const float* wk = (const float*)d_in[3];
    const float* wv = (const float*)d_in[4];
    const float* wo = (const float*)d_in[5];

    __bf16* ws  = (__bf16*)d_ws;
    __bf16* x   = ws;                           // 4096*1024
    __bf16* qb  = x   + (size_t)4096 * 1024;
    __bf16* kb  = qb  + (size_t)4096 * 1024;
    __bf16* vtb = kb  + (size_t)4096 * 1024;    // V^T: 1024 x 4096
    __bf16* ao  = x;                            // alias: attn out reuses x's buffer
    float*  out = (float*)d_out;

    // d_out scratch layout (all dead before wo_kernel writes C):
    // [0,6MB): bf16 wq/wk/wv; [6MB,6.5MB): rope cos/sin table; [8MB): counters.
    __bf16* wqb = (__bf16*)d_out;
    __bf16* wkb = wqb + (size_t)1024 * 1024;
    __bf16* wvb = wkb + (size_t)1024 * 1024;
    float2* tbl = (float2*)((char*)d_out + (size_t)6 * 1024 * 1024);
    int* counters = (int*)((char*)d_out + (size_t)8 * 1024 * 1024);

    pre_kernel<<<7424, 256, 0, stream>>>(wq, wk, wv, wqb, wkb, wvb, tbl, counters,
                                         tokens, gamma, x);

    qkv_kernel<<<dim3(32, 8, 3), 256, 0, stream>>>(x, wqb, wkb, wvb, qb, kb, vtb, tbl);

    attn_kernel<<<768, 256, 0, stream>>>(qb, kb, vtb, ao, counters);

    wo_kernel<<<dim3(32, 16), 256, 0, stream>>>(ao, wo, out);
}

// Round 12
// 193.584 us; speedup vs baseline: 1.0670x; 1.0457x over previous
//
#include <hip/hip_runtime.h>

typedef __bf16 bf16x8 __attribute__((ext_vector_type(8)));
typedef float f32x4 __attribute__((ext_vector_type(4)));

#define DIM 1024
#define NSEQ 2048

// async 16B global -> LDS DMA (lane-linear: wave-uniform LDS base + lane*16)
#define GL2LDS(g, l) __builtin_amdgcn_global_load_lds( \
    (const __attribute__((address_space(1))) void*)(g), \
    (__attribute__((address_space(3))) void*)(l), 16, 0, 0)

#define MFMA16(a, b, c) __builtin_amdgcn_mfma_f32_16x16x32_bf16(a, b, c, 0, 0, 0)

// ---------------- fp32 -> bf16 weight conversion (single weight) ----------------
__global__ __launch_bounds__(256) void cvt_kernel(const float* __restrict__ s,
                                                  __bf16* __restrict__ d) {
    int i = (blockIdx.x * 256 + threadIdx.x) * 4;
    float4 f = *(const float4*)(s + i);
    union { uint2 u; __bf16 h[4]; } p;
    p.h[0] = (__bf16)f.x; p.h[1] = (__bf16)f.y;
    p.h[2] = (__bf16)f.z; p.h[3] = (__bf16)f.w;
    *(uint2*)(d + i) = p.u;
}

// ---------------- fused pre-pass: cvt wq/wk/wv + rope cos/sin table + rmsnorm ---
__global__ __launch_bounds__(256) void pre_kernel(const float* __restrict__ wq,
                                                  const float* __restrict__ wk,
                                                  const float* __restrict__ wv,
                                                  __bf16* __restrict__ dq,
                                                  __bf16* __restrict__ dk,
                                                  __bf16* __restrict__ dv,
                                                  float2* __restrict__ tbl,
                                                  int* __restrict__ counters,
                                                  const float* __restrict__ x,
                                                  const float* __restrict__ g,
                                                  __bf16* __restrict__ xo) {
    int bid = blockIdx.x;
    int t = threadIdx.x;
    if (bid == 0 && t < 8) counters[t] = 0;
    if (bid < 3072) {                    // weight conversion
        int slice = bid >> 10;
        const float* s = slice == 0 ? wq : (slice == 1 ? wk : wv);
        __bf16*      d = slice == 0 ? dq : (slice == 1 ? dk : dv);
        int i = ((bid & 1023) * 256 + t) * 4;
        float4 f = *(const float4*)(s + i);
        union { uint2 u; __bf16 h[4]; } p;
        p.h[0] = (__bf16)f.x; p.h[1] = (__bf16)f.y;
        p.h[2] = (__bf16)f.z; p.h[3] = (__bf16)f.w;
        *(uint2*)(d + i) = p.u;
    } else if (bid < 3328) {             // rope table: tbl[pos*32+dp] = {cos,sin}
        int e = (bid - 3072) * 256 + t;
        int pos = e >> 5, dp = e & 31;
        float inv = __expf(-(float)dp * (9.210340371976184f / 32.0f));
        float sn, cs;
        sincosf((float)pos * inv, &sn, &cs);
        tbl[e] = make_float2(cs, sn);
    } else {                             // RMSNorm row
        int row = bid - 3328;
        float4 xv = ((const float4*)(x + (size_t)row * DIM))[t];
        float ss = xv.x*xv.x + xv.y*xv.y + xv.z*xv.z + xv.w*xv.w;
        #pragma unroll
        for (int off = 32; off; off >>= 1) ss += __shfl_xor(ss, off, 64);
        __shared__ float red[4];
        if ((t & 63) == 0) red[t >> 6] = ss;
        __syncthreads();
        ss = red[0] + red[1] + red[2] + red[3];
        float r = rsqrtf(ss * (1.0f / 1024.0f) + 1.1920929e-07f);
        float4 gv = ((const float4*)g)[t];
        union { uint2 u; __bf16 h[4]; } p;
        p.h[0] = (__bf16)(xv.x * r * gv.x);
        p.h[1] = (__bf16)(xv.y * r * gv.y);
        p.h[2] = (__bf16)(xv.z * r * gv.z);
        p.h[3] = (__bf16)(xv.w * r * gv.w);
        *(uint2*)(xo + (size_t)row * DIM + t * 4) = p.u;
    }
}

// ---------------- shared GEMM body; swizzled LDS + optional fused RoPE ----------
// T2 fix (R7 pm: 9.4M conflict-cycles = 27% of qkv wall): the LDS tile stride is
// 64 bf16 = 128 B = 32 banks, so column reads were 16-way conflicted. Keep GL2LDS
// (lane-linear dest) but PRE-SWIZZLE THE GLOBAL SOURCE (m173): lane l fetches
// col-block (l&7)^((l>>3)&7); since staging row == l>>3 (mod 8), LDS[row][cb]
// holds G[row][cb^(row&7)]. Readers XOR col-block with lrow&7 -> 8 distinct 16B
// slots per 16-lane group (2-way = free), full bank coverage. Coalescing
// unchanged (same address set per 8-lane row group, lanes permuted).
template <typename CT, bool ROPE>
__device__ __forceinline__ void gemm_body(const __bf16* __restrict__ A,
                                          const __bf16* __restrict__ B,
                                          CT* __restrict__ C,
                                          int mb, int nb, int ldc, float scale,
                                          __bf16* As, __bf16* Bs,
                                          const float2* __restrict__ tbl) {
    int t = threadIdx.x;
    int w = t >> 6, l = t & 63;
    int wm = (w >> 1) * 64, wn = (w & 1) * 64;   // wave 2x2 grid, each 64x64
    int lrow = l & 15, lq = l >> 4;
    int sw = lrow & 7;                           // read-side XOR key
    f32x4 acc[4][4] = {};

    int srow = w * 32 + (l >> 3);
    int sc8 = ((l & 7) ^ ((l >> 3) & 7)) * 8;    // source pre-swizzle
    const __bf16* gA = A + (size_t)(mb * 128 + srow) * 1024 + sc8;
    const __bf16* gB = B + (size_t)(nb * 128 + srow) * 1024 + sc8;
    __bf16* lA = As + (size_t)(w * 32) * 64;     // + c*8*64
    __bf16* lB = Bs + (size_t)(w * 32) * 64;

    for (int kt = 0; kt < 16; ++kt) {
        int k0 = kt * 64;
        #pragma unroll
        for (int c = 0; c < 4; ++c) {
            GL2LDS(gA + (size_t)c * 8 * 1024 + k0, lA + c * 8 * 64);
            GL2LDS(gB + (size_t)c * 8 * 1024 + k0, lB + c * 8 * 64);
        }
        __syncthreads();    // drains DMA, publishes tile
        #pragma unroll
        for (int ch = 0; ch < 2; ++ch) {
            bf16x8 af[4], bfr[4];
            #pragma unroll
            for (int i = 0; i < 4; ++i)
                af[i] = *(const bf16x8*)&As[(wm + i * 16 + lrow) * 64 + ((ch * 4 + lq) ^ sw) * 8];
            #pragma unroll
            for (int i = 0; i < 4; ++i)
                bfr[i] = *(const bf16x8*)&Bs[(wn + i * 16 + lrow) * 64 + ((ch * 4 + lq) ^ sw) * 8];
            #pragma unroll
            for (int rt = 0; rt < 4; ++rt)
                #pragma unroll
                for (int ct = 0; ct < 4; ++ct)
                    acc[rt][ct] = MFMA16(af[rt], bfr[ct], acc[rt][ct]);
        }
        __syncthreads();
    }
    #pragma unroll
    for (int rt = 0; rt < 4; ++rt)
        #pragma unroll
        for (int ct = 0; ct < 4; ++ct) {
            int colg = nb * 128 + wn + ct * 16 + lrow;
            int dp = ((ct * 16 + lrow) & 63) >> 1;   // pair index within head
            #pragma unroll
            for (int r = 0; r < 4; ++r) {
                int rowg = mb * 128 + wm + rt * 16 + lq * 4 + r;
                float v = acc[rt][ct][r] * scale;
                if constexpr (ROPE) {
                    float p = __shfl_xor(v, 1, 64);  // paired column, same row
                    float2 cs = tbl[((rowg & (NSEQ - 1)) << 5) + dp];
                    v = (lrow & 1) ? (v * cs.x + p * cs.y)   // odd col: x2 c + x1 s
                                   : (v * cs.x - p * cs.y);  // even col: x1 c - x2 s
                }
                C[(size_t)rowg * ldc + colg] = (CT)v;
            }
        }
}

// Fused QKV projections (+RoPE on q,k): grid (32, 8, 3) -> 768 blocks = 3/CU.
// Q scale folds BOTH 1/sqrt(64) AND log2(e): softmax runs in the exp2 domain.
__global__ __launch_bounds__(256) void qkv_kernel(const __bf16* __restrict__ x,
                                                  const __bf16* __restrict__ wq,
                                                  const __bf16* __restrict__ wk,
                                                  const __bf16* __restrict__ wv,
                                                  __bf16* __restrict__ qb,
                                                  __bf16* __restrict__ kb,
                                                  __bf16* __restrict__ vtb,
                                                  const float2* __restrict__ tbl) {
    __shared__ __bf16 As[128 * 64];
    __shared__ __bf16 Bs[128 * 64];
    int bm = blockIdx.x, bn = blockIdx.y, z = blockIdx.z;
    if (z == 0)      gemm_body<__bf16, true >(x,  wq, qb,  bm, bn, 1024,
                                       0.125f * 1.44269504088896340736f, As, Bs, tbl);
    else if (z == 1) gemm_body<__bf16, true >(x,  wk, kb,  bm, bn, 1024, 1.0f, As, Bs, tbl);
    else             gemm_body<__bf16, false>(wv, x,  vtb, bn, bm, 4096, 1.0f, As, Bs, tbl);
}

// Output projection: 128x64 tiles -> grid (32,16) = 512 blocks = 2 blocks/CU.
// Same source-preswizzle + read-XOR as gemm_body.
__global__ __launch_bounds__(256) void wo_kernel(const __bf16* __restrict__ A,
                                                 const __bf16* __restrict__ B,
                                                 float* __restrict__ C) {
    __shared__ __bf16 As[128 * 64];
    __shared__ __bf16 Bs[64 * 64];
    int mb = blockIdx.x, nb = blockIdx.y;
    int t = threadIdx.x;
    int w = t >> 6, l = t & 63;
    int wm = (w >> 1) * 64, wn = (w & 1) * 32;
    int lrow = l & 15, lq = l >> 4;
    int sw = lrow & 7;
    f32x4 acc[4][2] = {};

    int srowA = w * 32 + (l >> 3);       // A staging rows (4 calls x 8 rows)
    int srowB = w * 16 + (l >> 3);       // B staging rows (2 calls x 8 rows)
    int sc8 = ((l & 7) ^ ((l >> 3) & 7)) * 8;    // source pre-swizzle
    const __bf16* gA = A + (size_t)(mb * 128 + srowA) * 1024 + sc8;
    const __bf16* gB = B + (size_t)(nb * 64 + srowB) * 1024 + sc8;
    __bf16* lA = As + (size_t)(w * 32) * 64;
    __bf16* lB = Bs + (size_t)(w * 16) * 64;

    for (int kt = 0; kt < 16; ++kt) {
        int k0 = kt * 64;
        #pragma unroll
        for (int c = 0; c < 4; ++c)
            GL2LDS(gA + (size_t)c * 8 * 1024 + k0, lA + c * 8 * 64);
        #pragma unroll
        for (int c = 0; c < 2; ++c)
            GL2LDS(gB + (size_t)c * 8 * 1024 + k0, lB + c * 8 * 64);
        __syncthreads();
        #pragma unroll
        for (int ch = 0; ch < 2; ++ch) {
            bf16x8 af[4], bfr[2];
            #pragma unroll
            for (int i = 0; i < 4; ++i)
                af[i] = *(const bf16x8*)&As[(wm + i * 16 + lrow) * 64 + ((ch * 4 + lq) ^ sw) * 8];
            #pragma unroll
            for (int i = 0; i < 2; ++i)
                bfr[i] = *(const bf16x8*)&Bs[(wn + i * 16 + lrow) * 64 + ((ch * 4 + lq) ^ sw) * 8];
            #pragma unroll
            for (int rt = 0; rt < 4; ++rt)
                #pragma unroll
                for (int ct = 0; ct < 2; ++ct)
                    acc[rt][ct] = MFMA16(af[rt], bfr[ct], acc[rt][ct]);
        }
        __syncthreads();
    }
    #pragma unroll
    for (int rt = 0; rt < 4; ++rt)
        #pragma unroll
        for (int ct = 0; ct < 2; ++ct)
            #pragma unroll
            for (int r = 0; r < 4; ++r) {
                int row = mb * 128 + wm + rt * 16 + lq * 4 + r;
                int col = nb * 64 + wn + ct * 16 + lrow;
                C[(size_t)row * 1024 + col] = acc[rt][ct][r];
            }
}

// ---------------- Causal flash attention v5c (unchanged from R7, passed 51.4us) -
__global__ __launch_bounds__(256, 3) void attn_kernel(const __bf16* __restrict__ q,
                                                      const __bf16* __restrict__ kk,
                                                      const __bf16* __restrict__ vt,
                                                      __bf16* __restrict__ o,
                                                      int* __restrict__ counters) {
    int xcd = blockIdx.x & 7;            // dispatch round-robins over XCDs
    int t = threadIdx.x;
    int w = t >> 6, l = t & 63;
    int lrow = l & 15, lq = l >> 4;
    int rw = (w & 1) * 32;               // wave's q-row offset within the item
    int par = w >> 1;                    // key-tile parity this wave handles
    int row0 = t >> 3;                   // staging row 0..31 (also +32)
    int cb = t & 7;                      // staging 16B col-block 0..7

    __shared__ __bf16 Kt[2][64 * 64];    // [parity][key][d], swizzled
    __shared__ __bf16 Vs[2][64 * 64];    // [parity][d][key], swizzled
    __shared__ __bf16 Ps[4][32 * 72];    // per-wave P^T strip; doubles as merge scratch
    __shared__ int s_item;
    __bf16* pw = Ps[w];

    for (;;) {
        if (t == 0) s_item = atomicAdd(&counters[xcd], 1);
        __syncthreads();                 // broadcast item; fences LDS reuse
        int item = s_item;
        if (item >= 128) break;
        int iq = 31 - (item >> 2);       // 64-row q-tile, long-first (LPT)
        int bh = xcd * 4 + (item & 3);   // 4 (b,h) pairs resident per XCD (L2)
        int h = bh & 15;
        int b = bh >> 4;
        int rowbase = b * NSEQ;

        const __bf16* kbase = kk + (size_t)rowbase * DIM + h * 64;
        const __bf16* vbase = vt + (size_t)(h * 64) * 4096 + b * 2048;

        // Q fragments: 2 groups of 16 qrows (wave covers 32 rows)
        bf16x8 qf[2][2];
        #pragma unroll
        for (int g = 0; g < 2; ++g) {
            const __bf16* qp = q + (size_t)(rowbase + iq * 64 + rw + g * 16 + lrow) * DIM + h * 64;
            qf[g][0] = *(const bf16x8*)(qp + lq * 8);
            qf[g][1] = *(const bf16x8*)(qp + 32 + lq * 8);
        }

        f32x4 oacc[2][4] = {};           // O^T per group: [d-chunk], col = qrow
        float m_r[2] = {-1e30f, -1e30f};
        float l_r[2] = {0.0f, 0.0f};

        const __bf16* kg = kbase + (size_t)row0 * DIM + cb * 8;
        const __bf16* vg = vbase + (size_t)row0 * 4096 + cb * 8;
        int dsw0 = (row0 * 8 + (cb ^ (row0 & 7))) * 8;        // swizzled elem offset
        int dsw1 = ((row0 + 32) * 8 + (cb ^ (row0 & 7))) * 8; // (row0+32)&7 == row0&7

        // prologue: stage tile 0 -> buf0, tile 1 -> buf1 (if it exists)
        uint4 k0a, k0b, v0a, v0b, k1a, k1b, v1a, v1b;
        k0a = *(const uint4*)(kg);
        k0b = *(const uint4*)(kg + (size_t)32 * DIM);
        v0a = *(const uint4*)(vg);
        v0b = *(const uint4*)(vg + (size_t)32 * 4096);
        if (iq >= 1) {
            k1a = *(const uint4*)(kg + (size_t)64 * DIM);
            k1b = *(const uint4*)(kg + (size_t)96 * DIM);
            v1a = *(const uint4*)(vg + 64);
            v1b = *(const uint4*)(vg + (size_t)32 * 4096 + 64);
        }
        *(uint4*)&Kt[0][dsw0] = k0a; *(uint4*)&Kt[0][dsw1] = k0b;
        *(uint4*)&Vs[0][dsw0] = v0a; *(uint4*)&Vs[0][dsw1] = v0b;
        if (iq >= 1) {
            *(uint4*)&Kt[1][dsw0] = k1a; *(uint4*)&Kt[1][dsw1] = k1b;
            *(uint4*)&Vs[1][dsw0] = v1a; *(uint4*)&Vs[1][dsw1] = v1b;
        }
        __syncthreads();

        int R = (iq + 2) >> 1;           // rounds = ceil((iq+1)/2)
        for (int rd = 0; rd < R; ++rd) {
            int jt = 2 * rd + par;       // this wave's key-tile
            bool pf = (rd + 1 < R);      // block-uniform
            if (pf) {                    // prefetch next round's tile pair
                int je = 2 * rd + 2;
                size_t ko = (size_t)je * 64 * DIM;
                k0a = *(const uint4*)(kg + ko);
                k0b = *(const uint4*)(kg + ko + (size_t)32 * DIM);
                v0a = *(const uint4*)(vg + je * 64);
                v0b = *(const uint4*)(vg + (size_t)32 * 4096 + je * 64);
                if (je + 1 <= iq) {
                    k1a = *(const uint4*)(kg + ko + (size_t)64 * DIM);
                    k1b = *(const uint4*)(kg + ko + (size_t)96 * DIM);
                    v1a = *(const uint4*)(vg + je * 64 + 64);
                    v1b = *(const uint4*)(vg + (size_t)32 * 4096 + je * 64 + 64);
                }
            }
            if (jt <= iq) {              // wave-uniform: inactive only in last round
                const __bf16* Kb = Kt[par];
                const __bf16* Vb = Vs[par];
                int sw = lrow & 7;
                // QK^T: K fragment read ONCE, used by both q-row groups
                f32x4 st[2][4];
                __builtin_amdgcn_s_setprio(1);
                #pragma unroll
                for (int ct = 0; ct < 4; ++ct) {
                    int rr = (ct * 16 + lrow) * 8;
                    bf16x8 ka0 = *(const bf16x8*)&Kb[(rr + (lq ^ sw)) * 8];
                    bf16x8 ka1 = *(const bf16x8*)&Kb[(rr + ((4 + lq) ^ sw)) * 8];
                    #pragma unroll
                    for (int g = 0; g < 2; ++g) {
                        f32x4 z = {};
                        z = MFMA16(ka0, qf[g][0], z);
                        z = MFMA16(ka1, qf[g][1], z);
                        st[g][ct] = z;   // key = ct*16+lq*4+r, qrow(local) = lrow
                    }
                }
                __builtin_amdgcn_s_setprio(0);
                if (jt == iq) {          // causal mask on diagonal tile
                    #pragma unroll
                    for (int g = 0; g < 2; ++g) {
                        int qrel = rw + g * 16 + lrow;
                        #pragma unroll
                        for (int ct = 0; ct < 4; ++ct)
                            #pragma unroll
                            for (int r = 0; r < 4; ++r)
                                if (ct * 16 + lq * 4 + r > qrel) st[g][ct][r] = -3.0e38f;
                    }
                }
                // online softmax (exp2 domain) per group
                #pragma unroll
                for (int g = 0; g < 2; ++g) {
                    float m0 = fmaxf(fmaxf(st[g][0][0], st[g][0][1]), fmaxf(st[g][0][2], st[g][0][3]));
                    float m1 = fmaxf(fmaxf(st[g][1][0], st[g][1][1]), fmaxf(st[g][1][2], st[g][1][3]));
                    float m2 = fmaxf(fmaxf(st[g][2][0], st[g][2][1]), fmaxf(st[g][2][2], st[g][2][3]));
                    float m3 = fmaxf(fmaxf(st[g][3][0], st[g][3][1]), fmaxf(st[g][3][2], st[g][3][3]));
                    float mx = fmaxf(fmaxf(m0, m1), fmaxf(m2, m3));
                    mx = fmaxf(mx, __shfl_xor(mx, 16, 64));
                    mx = fmaxf(mx, __shfl_xor(mx, 32, 64));
                    if (!__all(mx - m_r[g] <= 8.0f)) {   // defer-max (T13)
                        float mnew = fmaxf(m_r[g], mx);
                        float alpha = __builtin_amdgcn_exp2f(m_r[g] - mnew);
                        l_r[g] *= alpha;
                        #pragma unroll
                        for (int ct = 0; ct < 4; ++ct)
                            #pragma unroll
                            for (int r = 0; r < 4; ++r) oacc[g][ct][r] *= alpha;
                        m_r[g] = mnew;
                    }
                    float ps = 0.0f;
                    #pragma unroll
                    for (int ct = 0; ct < 4; ++ct)
                        #pragma unroll
                        for (int r = 0; r < 4; ++r) {
                            float p = __builtin_amdgcn_exp2f(st[g][ct][r] - m_r[g]);
                            st[g][ct][r] = p;
                            ps += p;
                        }
                    ps += __shfl_xor(ps, 16, 64);
                    ps += __shfl_xor(ps, 32, 64);
                    l_r[g] += ps;
                }
                // P^T -> per-wave strip (stride 72 = 16B-aligned rows)
                #pragma unroll
                for (int g = 0; g < 2; ++g)
                    #pragma unroll
                    for (int ct = 0; ct < 4; ++ct) {
                        union { uint2 u; __bf16 h4[4]; } pk;
                        #pragma unroll
                        for (int r = 0; r < 4; ++r) pk.h4[r] = (__bf16)st[g][ct][r];
                        *(uint2*)&pw[(g * 16 + lrow) * 72 + ct * 16 + lq * 4] = pk.u;
                    }
                bf16x8 pb[2][2];
                #pragma unroll
                for (int g = 0; g < 2; ++g) {
                    pb[g][0] = *(const bf16x8*)&pw[(g * 16 + lrow) * 72 + lq * 8];
                    pb[g][1] = *(const bf16x8*)&pw[(g * 16 + lrow) * 72 + 32 + lq * 8];
                }
                // O^T += V^T * P^T: V fragment read ONCE, used by both groups
                __builtin_amdgcn_s_setprio(1);
                #pragma unroll
                for (int ct = 0; ct < 4; ++ct) {
                    int rr = (ct * 16 + lrow) * 8;
                    bf16x8 va0 = *(const bf16x8*)&Vb[(rr + (lq ^ sw)) * 8];
                    bf16x8 va1 = *(const bf16x8*)&Vb[(rr + ((4 + lq) ^ sw)) * 8];
                    #pragma unroll
                    for (int g = 0; g < 2; ++g) {
                        oacc[g][ct] = MFMA16(va0, pb[g][0], oacc[g][ct]);
                        oacc[g][ct] = MFMA16(va1, pb[g][1], oacc[g][ct]);
                    }
                }
                __builtin_amdgcn_s_setprio(0);
            }
            if (pf) {                    // publish next round's tiles
                __syncthreads();         // everyone done reading bufs
                *(uint4*)&Kt[0][dsw0] = k0a; *(uint4*)&Kt[0][dsw1] = k0b;
                *(uint4*)&Vs[0][dsw0] = v0a; *(uint4*)&Vs[0][dsw1] = v0b;
                if (2 * rd + 3 <= iq) {
                    *(uint4*)&Kt[1][dsw0] = k1a; *(uint4*)&Kt[1][dsw1] = k1b;
                    *(uint4*)&Vs[1][dsw0] = v1a; *(uint4*)&Vs[1][dsw1] = v1b;
                }
                __syncthreads();
            }
        }

        // ---- merge parity partials (flash combine) + store, via Ps as f32 scratch
        __syncthreads();                 // par-0 waves must finish reading their P
                                         // strips (scratch aliases Ps[0..1]) before
                                         // par-1 waves overwrite.
        float* sc = (float*)&Ps[0][0];               // 18432 B = 2 x 64 x 36 floats
        float* base = sc + (w & 1) * 2304 + l * 36;
        if (par == 1) {
            #pragma unroll
            for (int g = 0; g < 2; ++g)
                #pragma unroll
                for (int ct = 0; ct < 4; ++ct)
                    *(f32x4*)(base + g * 16 + ct * 4) = oacc[g][ct];
            base[32] = m_r[0]; base[33] = m_r[1];
            base[34] = l_r[0]; base[35] = l_r[1];
        }
        __syncthreads();
        if (par == 0) {
            #pragma unroll
            for (int g = 0; g < 2; ++g) {
                float mb = base[32 + g], lb = base[34 + g];
                float m = fmaxf(m_r[g], mb);
                float a  = __builtin_amdgcn_exp2f(m_r[g] - m);
                float bb = __builtin_amdgcn_exp2f(mb - m);
                float rcp = 1.0f / (a * l_r[g] + bb * lb);
                const size_t orow = (size_t)(rowbase + iq * 64 + rw + g * 16 + lrow) * DIM + h * 64;
                #pragma unroll
                for (int ct = 0; ct < 4; ++ct) {
                    f32x4 ob = *(const f32x4*)(base + g * 16 + ct * 4);
                    union { uint2 u; __bf16 h4[4]; } pk;
                    #pragma unroll
                    for (int r = 0; r < 4; ++r)
                        pk.h4[r] = (__bf16)((a * oacc[g][ct][r] + bb * ob[r]) * rcp);
                    *(uint2*)(o + orow + ct * 16 + lq * 4) = pk.u;
                }
            }
        }
    }
}

extern "C" void kernel_launch(void* const* d_in, const int* in_sizes, int n_in,
                              void* d_out, int out_size, void* d_ws, size_t ws_size,
                              hipStream_t stream) {
    const float* tokens = (const float*)d_in[0];
    const float* gamma  = (const float*)d_in[1];
    const float* wq = (const float*)d_in[2];
    const float* wk = (const float*)d_in[3];
    const float* wv = (const float*)d_in[4];
    const float* wo = (const float*)d_in[5];

    __bf16* ws  = (__bf16*)d_ws;
    __bf16* x   = ws;                           // 4096*1024
    __bf16* qb  = x   + (size_t)4096 * 1024;
    __bf16* kb  = qb  + (size_t)4096 * 1024;
    __bf16* vtb = kb  + (size_t)4096 * 1024;    // V^T: 1024 x 4096
    __bf16* ao  = x;                            // alias: attn out reuses x's buffer
    __bf16* wob = qb;                           // alias: qb dead after attn
    float*  out = (float*)d_out;

    // d_out scratch layout (all dead before wo_kernel writes C):
    // [0,6MB): bf16 wq/wk/wv; [6MB,6.5MB): rope cos/sin table; [8MB): counters.
    __bf16* wqb = (__bf16*)d_out;
    __bf16* wkb = wqb + (size_t)1024 * 1024;
    __bf16* wvb = wkb + (size_t)1024 * 1024;
    float2* tbl = (float2*)((char*)d_out + (size_t)6 * 1024 * 1024);
    int* counters = (int*)((char*)d_out + (size_t)8 * 1024 * 1024);

    pre_kernel<<<7424, 256, 0, stream>>>(wq, wk, wv, wqb, wkb, wvb, tbl, counters,
                                         tokens, gamma, x);

    qkv_kernel<<<dim3(32, 8, 3), 256, 0, stream>>>(x, wqb, wkb, wvb, qb, kb, vtb, tbl);

    attn_kernel<<<768, 256, 0, stream>>>(qb, kb, vtb, ao, counters);

    cvt_kernel<<<1024, 256, 0, stream>>>(wo, wob);   // qb region is dead now

    wo_kernel<<<dim3(32, 16), 256, 0, stream>>>(ao, wob, out);
}